// Round 5
// baseline (466.791 us; speedup 1.0000x reference)
//
#include <hip/hip_runtime.h>

#define NN 8192
#define DD 256
#define FF 128
#define BB 4096
#define NSPLIT 8
#define KCHUNK (NN / NSPLIT)   // 1024 keys per split-K chunk
#define NITER (KCHUNK / 64)    // 16 key-tiles per chunk

typedef unsigned short ushortT;
typedef __attribute__((ext_vector_type(8))) short bf16x8;
typedef __attribute__((ext_vector_type(4))) float f32x4;

__device__ __forceinline__ ushortT f2bf(float f) {   // fp32 -> bf16 RNE
  unsigned u = __float_as_uint(f);
  return (ushortT)((u + 0x7FFFu + ((u >> 16) & 1u)) >> 16);
}
__device__ __forceinline__ float bf2f(ushortT h) {
  return __uint_as_float(((unsigned)h) << 16);
}

// async global->LDS DMA, 16 B per lane. LDS dest must be wave-uniform base + lane*16.
__device__ __forceinline__ void cp16(const ushortT* g, ushortT* l) {
  __builtin_amdgcn_global_load_lds(
      (const __attribute__((address_space(1))) unsigned*)g,
      (__attribute__((address_space(3))) unsigned*)l, 16, 0, 0);
}

// ---------------- unique(x) compaction ----------------

__global__ __launch_bounds__(256) void init_kernel(int* flags, int* cnt) {
  int i = blockIdx.x * 256 + threadIdx.x;
  flags[i] = 0;
  if (i == 0) *cnt = 0;
}

__global__ __launch_bounds__(256) void scatter_kernel(const int* __restrict__ x, int* flags) {
  int b = blockIdx.x * 256 + threadIdx.x;
  flags[x[b]] = 1;
}

__global__ __launch_bounds__(256) void compact_kernel(const int* __restrict__ flags, int* cnt,
                                                      int* list, int* slot) {
  int i = blockIdx.x * 256 + threadIdx.x;
  if (flags[i]) {
    int pos = atomicAdd(cnt, 1);
    list[pos] = i;
    slot[i] = pos;
  }
}

// ---------------- pack adj rows of unique slots into bitmasks ----------------

__global__ __launch_bounds__(256) void pack_kernel(const int* __restrict__ adj,
                                                   const int* __restrict__ list,
                                                   const int* __restrict__ cntp,
                                                   unsigned* __restrict__ pk) {
  const int s = blockIdx.x >> 2;
  const int kc = (blockIdx.x & 3) * 2048;
  if (s >= *cntp) return;                    // uniform per block
  const int w = threadIdx.x >> 6, l = threadIdx.x & 63;
  const int* base = adj + (size_t)list[s] * NN + kc + w * 512;
  unsigned long long* dst = (unsigned long long*)(pk + s * 256 + (kc >> 5) + w * 16);
#pragma unroll
  for (int i = 0; i < 8; ++i) {
    unsigned long long b = __ballot(base[i * 64 + l] > 0);  // bit l = key ...+i*64+l
    if (l == 0) dst[i] = b;
  }
}

// ---------------- Wh = embedding @ W, emitted as bf16 hi/lo split ----------------

__global__ __launch_bounds__(256) void wh_kernel(const float* __restrict__ emb,
                                                 const float* __restrict__ W,
                                                 ushortT* __restrict__ Whh,
                                                 ushortT* __restrict__ Whl) {
  __shared__ float Es[32 * 65];
  __shared__ float Ws[64 * 128];
  const int t = threadIdx.x;
  const int r0 = blockIdx.x * 32;
  const int rg = t >> 5;
  const int cg = t & 31;
  float4 acc[4] = {{0,0,0,0},{0,0,0,0},{0,0,0,0},{0,0,0,0}};
  for (int kc = 0; kc < DD; kc += 64) {
    __syncthreads();
    for (int i = 0; i < 8; ++i) {
      int idx = t + 256 * i;
      int r = idx >> 6, k = idx & 63;
      Es[r * 65 + k] = emb[(r0 + r) * DD + kc + k];
    }
    for (int i = 0; i < 8; ++i) {
      int idx = t + 256 * i;
      int kr = idx >> 5, c4 = (idx & 31) * 4;
      *(float4*)&Ws[kr * 128 + c4] = *(const float4*)&W[(kc + kr) * 128 + c4];
    }
    __syncthreads();
    for (int k = 0; k < 64; ++k) {
      float4 b = *(const float4*)&Ws[k * 128 + cg * 4];
#pragma unroll
      for (int i = 0; i < 4; ++i) {
        float a = Es[(rg * 4 + i) * 65 + k];
        acc[i].x += a * b.x; acc[i].y += a * b.y;
        acc[i].z += a * b.z; acc[i].w += a * b.w;
      }
    }
  }
#pragma unroll
  for (int i = 0; i < 4; ++i) {
    int row = r0 + rg * 4 + i;
    float v[4] = {acc[i].x, acc[i].y, acc[i].z, acc[i].w};
    ushort4 hh, ll;
    ushortT* hp = (ushortT*)&hh;
    ushortT* lp = (ushortT*)&ll;
#pragma unroll
    for (int k = 0; k < 4; ++k) {
      ushortT h = f2bf(v[k]);
      hp[k] = h;
      lp[k] = f2bf(v[k] - bf2f(h));
    }
    *(ushort4*)&Whh[row * FF + cg * 4] = hh;
    *(ushort4*)&Whl[row * FF + cg * 4] = ll;
  }
}

// ---------------- WhT = Whh^T (128 x 8192), 64x64 tiles ----------------

__global__ __launch_bounds__(256) void transpose_kernel(const ushortT* __restrict__ A,
                                                        ushortT* __restrict__ At) {
  __shared__ ushortT tile[64 * 72];
  const int t = threadIdx.x;
  const int r0 = (blockIdx.x >> 1) * 64, c0 = (blockIdx.x & 1) * 64;
#pragma unroll
  for (int i = 0; i < 2; ++i) {
    int idx = t + 256 * i;
    int r = idx >> 3, cb = idx & 7;
    *(bf16x8*)&tile[r * 72 + ((cb ^ ((r >> 3) & 7)) * 8)] =
        *(const bf16x8*)&A[(size_t)(r0 + r) * FF + c0 + cb * 8];
  }
  __syncthreads();
#pragma unroll
  for (int i = 0; i < 2; ++i) {
    int idx = t + 256 * i;
    int f = idx >> 3, r8 = idx & 7;
    bf16x8 v;
#pragma unroll
    for (int u = 0; u < 8; ++u) {
      int row = r8 * 8 + u;
      v[u] = (short)tile[row * 72 + (((f >> 3) ^ ((row >> 3) & 7)) * 8) + (f & 7)];
    }
    *(bf16x8*)&At[(size_t)(c0 + f) * NN + r0 + r8 * 8] = v;
  }
}

// ---------------- MFMA flash attention: async-DMA dbuf K, bit masks ----------------
// Block = 4 waves, 64 q-rows, one 1024-key chunk. K-tiles staged via
// global_load_lds (zero VGPR landing), double-buffered. Loop order:
//   barrier (drains DMA for buf[cur]) -> issue DMA for buf[1-cur] -> compute(cur)
// so the DMA overlaps the full compute phase and is drained at the NEXT barrier.
// XOR swizzle applied on the GLOBAL address side (DMA needs lane-linear LDS dest):
// LDS slot (r, m) holds global chunk (r, m ^ (r&7)); read of chunk q at row r
// uses slot q ^ (r&7)  — read formulas identical to the verified R4 kernel.
// Masks from packed bits (L2); V-frags from WhT (16 KB/iter, L1-resident).
// Layouts: A[m=lane&15][k=quad*8+j]; B[k=quad*8+j][n=lane&15]; C/D row=quad*4+reg, col=lane&15.

__device__ __forceinline__ void stage_tile(const ushortT* __restrict__ Whh,
                                           const ushortT* __restrict__ Whl,
                                           short* KhB, short* KlB, int kt, int t) {
#pragma unroll
  for (int i = 0; i < 4; ++i) {
    int idx = t + 256 * i;
    int r = idx >> 4, m = idx & 15;
    int q = m ^ (r & 7);
    cp16(Whh + (size_t)(kt + r) * FF + q * 8, (ushortT*)&KhB[idx * 8]);
    cp16(Whl + (size_t)(kt + r) * FF + q * 8, (ushortT*)&KlB[idx * 8]);
  }
}

__global__ __launch_bounds__(256, 2) void attn_kernel(
    const ushortT* __restrict__ Whh, const ushortT* __restrict__ Whl,
    const ushortT* __restrict__ WhT, const unsigned* __restrict__ pk,
    const int* __restrict__ list, const int* __restrict__ cntp,
    float* __restrict__ Opart, float* __restrict__ mpart, float* __restrict__ lpart) {
  __shared__ short Kh[2][64 * 128];
  __shared__ short Kl[2][64 * 128];
  __shared__ short Ps[4][16 * 72];
  __shared__ int nid[64];

  const int cnt = *cntp;
  const int qblk = blockIdx.x >> 3, chunk = blockIdx.x & 7;
  const int q0 = qblk * 64;
  if (q0 >= cnt) return;                 // uniform: whole block exits

  const int t = threadIdx.x;
  if (t < 64) nid[t] = list[min(q0 + t, cnt - 1)];  // tail rows dup cnt-1 (junk slots unused)
  const int kt0 = chunk * KCHUNK;
  stage_tile(Whh, Whl, Kh[0], Kl[0], kt0, t);       // prologue DMA -> buf 0
  __syncthreads();                                  // nid visible + buf0 DMA drained

  const int w = t >> 6, l = t & 63, quad = l >> 4, c = l & 15;

  // Q fragments in registers for the whole K loop (A-operand: row = c)
  const size_t qr = (size_t)nid[w * 16 + c] * FF;
  bf16x8 qh[4], ql[4];
#pragma unroll
  for (int ks = 0; ks < 4; ++ks) {
    qh[ks] = *(const bf16x8*)(Whh + qr + ks * 32 + quad * 8);
    ql[ks] = *(const bf16x8*)(Whl + qr + ks * 32 + quad * 8);
  }
  int prow[4];
#pragma unroll
  for (int r = 0; r < 4; ++r) prow[r] = min(q0 + w * 16 + quad * 4 + r, cnt - 1);

  float m[4], lr[4];
#pragma unroll
  for (int r = 0; r < 4; ++r) { m[r] = -1e30f; lr[r] = 0.f; }
  f32x4 O[8] = {{0,0,0,0},{0,0,0,0},{0,0,0,0},{0,0,0,0},
                {0,0,0,0},{0,0,0,0},{0,0,0,0},{0,0,0,0}};

  for (int it = 0; it < NITER; ++it) {
    const int kt = kt0 + it * 64;
    const int cur = it & 1;
    __syncthreads();                     // drains buf[cur] DMA; closes prev-iter reads
    // ---- issue next tile's DMA into the other buffer (drained at NEXT barrier) ----
    if (it + 1 < NITER)
      stage_tile(Whh, Whl, Kh[1 - cur], Kl[1 - cur], kt + 64, t);
    // ---- mask words: 64 bits per row, broadcast loads (L2) ----
    unsigned mw0[4], mw1[4];
#pragma unroll
    for (int r = 0; r < 4; ++r) {
      uint2 mm = *(const uint2*)(pk + (size_t)prow[r] * 256 + (kt >> 5));
      mw0[r] = mm.x; mw1[r] = mm.y;
    }

    // ---- S = Q.K^T over 4 key-16 tiles, 3-term hi/lo, K from LDS ----
    f32x4 sacc[4];
#pragma unroll
    for (int nt = 0; nt < 4; ++nt) {
      const int rb = (nt * 16 + c) * 128;
      f32x4 a = {0, 0, 0, 0};
#pragma unroll
      for (int ks = 0; ks < 4; ++ks) {
        const int off = rb + (((ks * 4 + quad) ^ (c & 7)) * 8);
        bf16x8 bh = *(const bf16x8*)&Kh[cur][off];
        bf16x8 bl = *(const bf16x8*)&Kl[cur][off];
        a = __builtin_amdgcn_mfma_f32_16x16x32_bf16(qh[ks], bh, a, 0, 0, 0);
        a = __builtin_amdgcn_mfma_f32_16x16x32_bf16(ql[ks], bh, a, 0, 0, 0);
        a = __builtin_amdgcn_mfma_f32_16x16x32_bf16(qh[ks], bl, a, 0, 0, 0);
      }
      sacc[nt] = a;
    }

    // ---- in-wave masked online softmax ----
    float rmax[4];
#pragma unroll
    for (int r = 0; r < 4; ++r) {
      float v = -1e30f;
#pragma unroll
      for (int nt = 0; nt < 4; ++nt) {
        unsigned bit = ((nt < 2 ? mw0[r] : mw1[r]) >> ((nt & 1) * 16 + c)) & 1u;
        v = fmaxf(v, bit ? sacc[nt][r] : -1e30f);
      }
      rmax[r] = v;
    }
#pragma unroll
    for (int mk = 1; mk <= 8; mk <<= 1)
#pragma unroll
      for (int r = 0; r < 4; ++r) rmax[r] = fmaxf(rmax[r], __shfl_xor(rmax[r], mk, 16));
    float sc[4], psum[4];
#pragma unroll
    for (int r = 0; r < 4; ++r) {
      float nm = fmaxf(m[r], rmax[r]);
      sc[r] = __expf(m[r] - nm);
      m[r] = nm;
      psum[r] = 0.f;
    }
#pragma unroll
    for (int nt = 0; nt < 4; ++nt)
#pragma unroll
      for (int r = 0; r < 4; ++r) {
        unsigned bit = ((nt < 2 ? mw0[r] : mw1[r]) >> ((nt & 1) * 16 + c)) & 1u;
        float p = bit ? __expf(sacc[nt][r] - m[r]) : 0.f;
        ushortT pb = f2bf(p);
        Ps[w][(quad * 4 + r) * 72 + nt * 16 + c] = (short)pb;
        psum[r] += bf2f(pb);
      }
#pragma unroll
    for (int mk = 1; mk <= 8; mk <<= 1)
#pragma unroll
      for (int r = 0; r < 4; ++r) psum[r] += __shfl_xor(psum[r], mk, 16);
#pragma unroll
    for (int r = 0; r < 4; ++r) lr[r] = lr[r] * sc[r] + psum[r];

    // ---- O rescale + PV (A from per-wave Ps, B from WhT global/L1) ----
#pragma unroll
    for (int ft = 0; ft < 8; ++ft)
#pragma unroll
      for (int r = 0; r < 4; ++r) O[ft][r] *= sc[r];
    bf16x8 pa[2];
#pragma unroll
    for (int ks2 = 0; ks2 < 2; ++ks2)
      pa[ks2] = *(const bf16x8*)&Ps[w][c * 72 + ks2 * 32 + quad * 8];
#pragma unroll
    for (int ft = 0; ft < 8; ++ft) {
      const ushortT* vp = WhT + (size_t)(ft * 16 + c) * NN + kt + quad * 8;
#pragma unroll
      for (int ks2 = 0; ks2 < 2; ++ks2) {
        bf16x8 vb = *(const bf16x8*)(vp + ks2 * 32);
        O[ft] = __builtin_amdgcn_mfma_f32_16x16x32_bf16(pa[ks2], vb, O[ft], 0, 0, 0);
      }
    }
  }

  // ---- epilogue ----
  float* Op = Opart + (size_t)chunk * 4096 * FF;
#pragma unroll
  for (int ft = 0; ft < 8; ++ft)
#pragma unroll
    for (int r = 0; r < 4; ++r)
      Op[(size_t)(q0 + w * 16 + quad * 4 + r) * FF + ft * 16 + c] = O[ft][r];
  if (c == 0) {
#pragma unroll
    for (int r = 0; r < 4; ++r) {
      mpart[chunk * 4096 + q0 + w * 16 + quad * 4 + r] = m[r];
      lpart[chunk * 4096 + q0 + w * 16 + quad * 4 + r] = lr[r];
    }
  }
}

// ---------------- merge split-K partials, normalize, elu ----------------

__global__ __launch_bounds__(128) void combine_kernel(
    const float* __restrict__ Opart, const float* __restrict__ mpart,
    const float* __restrict__ lpart, float* __restrict__ h) {
  const int r = blockIdx.x;
  const int t = threadIdx.x;
  float mstar = -1e30f;
#pragma unroll
  for (int c = 0; c < NSPLIT; ++c) mstar = fmaxf(mstar, mpart[c * 4096 + r]);
  float lstar = 0.f, acc = 0.f;
#pragma unroll
  for (int c = 0; c < NSPLIT; ++c) {
    float wgt = __expf(mpart[c * 4096 + r] - mstar);
    lstar += wgt * lpart[c * 4096 + r];
    acc += wgt * Opart[((size_t)c * 4096 + r) * FF + t];
  }
  float v = acc / fmaxf(lstar, 1e-30f);
  h[r * FF + t] = v > 0.f ? v : expm1f(v);
}

// ---------------- gather by x, L2-normalize ----------------

__global__ __launch_bounds__(128) void out_kernel(const int* __restrict__ x,
                                                  const int* __restrict__ slot,
                                                  const float* __restrict__ h,
                                                  float* __restrict__ out) {
  const int b = blockIdx.x, t = threadIdx.x;
  const int s = slot[x[b]];
  float v = h[s * FF + t];
  float ss = v * v;
#pragma unroll
  for (int wd = 1; wd <= 32; wd <<= 1) ss += __shfl_xor(ss, wd);
  __shared__ float red[2];
  if ((t & 63) == 0) red[t >> 6] = ss;
  __syncthreads();
  float tot = red[0] + red[1];
  float scale = 1.f / fmaxf(sqrtf(tot), 1e-12f);
  out[b * FF + t] = v * scale;
}

// ---------------- launch ----------------

extern "C" void kernel_launch(void* const* d_in, const int* in_sizes, int n_in,
                              void* d_out, int out_size, void* d_ws, size_t ws_size,
                              hipStream_t stream) {
  const int*   x   = (const int*)d_in[0];
  const int*   adj = (const int*)d_in[1];
  const float* emb = (const float*)d_in[2];
  const float* W   = (const float*)d_in[3];
  float* out = (float*)d_out;

  char* base = (char*)d_ws;                              // ~27.6 MB total
  ushortT* Whh = (ushortT*)(base);                       //  0 .. 2 MB
  ushortT* Whl = (ushortT*)(base + 2097152);             //  2 .. 4 MB (dead after attn)
  float*   h   = (float*)(base + 2097152);               //  aliases Whl
  ushortT* WhT = (ushortT*)(base + 4194304);             //  4 .. 6 MB
  float* Opart = (float*)(base + 6291456);               //  6 .. 22.8 MB
  float* mpart = (float*)(base + 23068672);
  float* lpart = (float*)(base + 23199744);
  unsigned* pk = (unsigned*)(base + 23330816);           //  4 MB packed adj bits
  int*   flags = (int*)(base + 27525120);
  int*   list  = (int*)(base + 27557888);
  int*   slot  = (int*)(base + 27574272);
  int*   cnt   = (int*)(base + 27607040);
  (void)in_sizes; (void)n_in; (void)out_size; (void)ws_size;

  hipLaunchKernelGGL(init_kernel,      dim3(NN / 256), dim3(256), 0, stream, flags, cnt);
  hipLaunchKernelGGL(scatter_kernel,   dim3(BB / 256), dim3(256), 0, stream, x, flags);
  hipLaunchKernelGGL(compact_kernel,   dim3(NN / 256), dim3(256), 0, stream, flags, cnt, list, slot);
  hipLaunchKernelGGL(pack_kernel,      dim3(4096 * 4), dim3(256), 0, stream, adj, list, cnt, pk);
  hipLaunchKernelGGL(wh_kernel,        dim3(NN / 32),  dim3(256), 0, stream, emb, W, Whh, Whl);
  hipLaunchKernelGGL(transpose_kernel, dim3((NN / 64) * 2), dim3(256), 0, stream, Whh, WhT);
  hipLaunchKernelGGL(attn_kernel,      dim3((BB / 64) * NSPLIT), dim3(256), 0, stream,
                     Whh, Whl, WhT, pk, list, cnt, Opart, mpart, lpart);
  hipLaunchKernelGGL(combine_kernel,   dim3(4096), dim3(128), 0, stream, Opart, mpart, lpart, h);
  hipLaunchKernelGGL(out_kernel,       dim3(BB),   dim3(128), 0, stream, x, slot, h, out);
}